// Round 18
// baseline (202.500 us; speedup 1.0000x reference)
//
#include <hip/hip_runtime.h>
#include <cstdint>

#define NB 8
#define NC 96
#define NC2 192
#define NPT 3136    // 56*56
#define NK 9
#define NSPL 16     // j-splits
#define NLIST 16    // lists per row after in-wave half-merge
#define NDEP 9      // per-list depth (>= NK for superset guarantee)
#define NCAND 16    // pooled candidate count per row
#define NROWS (NB * NPT)
#define RST 104     // fnT row stride (96 fn + sq at [96] + pad)
#define FT_WSTR 76  // k_feat LDS per-ob stride
static constexpr float BN_EPS = 1e-5f;
typedef unsigned long long u64;
typedef float f32x16 __attribute__((ext_vector_type(16)));
typedef short short8 __attribute__((ext_vector_type(8)));

__device__ inline unsigned short f32_to_bf16_rne(float x) {
  unsigned u = __float_as_uint(x);
  unsigned r = (u + 0x7FFFu + ((u >> 16) & 1u)) >> 16;
  return (unsigned short)r;
}

__device__ inline unsigned score_to_key_exact(float s) {
  unsigned u = __float_as_uint(s);
  u ^= 0x80000000u | (unsigned)((int)u >> 31);  // monotone increasing map
  return ~u;                                    // descending score = ascending dist
}

__device__ inline u64 shfl64(u64 x, int src) {
  unsigned lo = __shfl((unsigned)x, src);
  unsigned hi = __shfl((unsigned)(x >> 32), src);
  return ((u64)hi << 32) | lo;
}

// ---------------- K1: fold BN into weights; bf16 hi/lo weight layouts ------------------
__global__ void k_fuse(const float* __restrict__ W1, const float* __restrict__ b1,
                       const float* __restrict__ g1, const float* __restrict__ be1,
                       const float* __restrict__ m1, const float* __restrict__ v1,
                       const float* __restrict__ Wg,
                       const float* __restrict__ W2, const float* __restrict__ b2,
                       const float* __restrict__ g2, const float* __restrict__ be2,
                       const float* __restrict__ m2, const float* __restrict__ v2,
                       float* __restrict__ W1s, float* __restrict__ b1f,
                       unsigned short* __restrict__ Wuvh, unsigned short* __restrict__ Wuvl,
                       unsigned short* __restrict__ W2h, unsigned short* __restrict__ W2l,
                       float* __restrict__ b2f) {
  int t = blockIdx.x * blockDim.x + threadIdx.x;
  int nth = gridDim.x * blockDim.x;
  for (int i = t; i < NC * NC; i += nth) {
    int ch = i / 1152, r = i % 1152;
    int ob = r / 72, r2 = r % 72;
    int cc = r2 / 6, oo = r2 % 6;
    int c = ch * 12 + cc, o = ob * 6 + oo;
    float inv = g1[o] / sqrtf(v1[o] + BN_EPS);
    W1s[i] = W1[o * NC + c] * inv;
  }
  for (int o = t; o < NC; o += nth) {
    float inv = g1[o] / sqrtf(v1[o] + BN_EPS);
    b1f[o] = b1[o] * inv + be1[o] - m1[o] * inv;
    float inv2v = g2[o] / sqrtf(v2[o] + BN_EPS);
    b2f[o] = b2[o] * inv2v + be2[o] - m2[o] * inv2v;
  }
  for (int i = t; i < 2 * NC2 * NC; i += nth) {
    int o4 = i / NC, c = i % NC;
    float val;
    if (o4 < NC2) val = Wg[o4 * NC2 + c] - Wg[o4 * NC2 + NC + c];
    else          val = Wg[(o4 - NC2) * NC2 + NC + c];
    unsigned short h = f32_to_bf16_rne(val);
    float hv = __uint_as_float(((unsigned)h) << 16);
    Wuvh[i] = h;
    Wuvl[i] = f32_to_bf16_rne(val - hv);
  }
  for (int i = t; i < NC * NC2; i += nth) {
    int o = i / NC2, c = i % NC2;
    float inv = g2[o] / sqrtf(v2[o] + BN_EPS);
    float val = W2[o * NC2 + c] * inv;
    unsigned short h = f32_to_bf16_rne(val);
    float hv = __uint_as_float(((unsigned)h) << 16);
    W2h[i] = h;
    W2l[i] = f32_to_bf16_rne(val - hv);
  }
}

// ------- K2: feat = BN(W1 x + b1) -> bf16 hi/lo rows; fnT f32 norm rows; hiT/loT -------
__global__ __launch_bounds__(64, 4) void k_feat(const float* __restrict__ x,
                                                const float* __restrict__ W1s,
                                                const float* __restrict__ b1f,
                                                unsigned short* __restrict__ fth,
                                                unsigned short* __restrict__ ftl,
                                                float* __restrict__ fnT,
                                                unsigned short* __restrict__ hiT,
                                                unsigned short* __restrict__ loT) {
  int bid = blockIdx.x;      // 1568
  int b = bid & 7;
  int ng = bid >> 3;         // 0..195
  int n0 = ng * 16;
  int lane = threadIdx.x;
  int ob = lane & 15, nq = lane >> 4;

  __shared__ float w_lds[16 * FT_WSTR];  // 4864 B
  __shared__ float f_lds[12 * 16];       // 768 B

  const float* xb = x + (size_t)b * NC * NPT;
  float acc[4][6];
#pragma unroll
  for (int oo = 0; oo < 6; ++oo) {
    float bv = b1f[ob * 6 + oo];
#pragma unroll
    for (int q = 0; q < 4; ++q) acc[q][oo] = bv;
  }

  for (int ch = 0; ch < 8; ++ch) {
    __syncthreads();
    {
      const float* wsrc = W1s + ch * 1152;
#pragma unroll
      for (int it = 0; it < 5; ++it) {
        int i = it * 256 + lane * 4;
        if (it < 4 || lane < 32) {
          float4 v = *(const float4*)&wsrc[i];
          *(float4*)&w_lds[(i / 72) * FT_WSTR + (i % 72)] = v;
        }
      }
#pragma unroll
      for (int it = 0; it < 3; ++it) {
        int i = it * 64 + lane;
        f_lds[i] = xb[(size_t)(ch * 12 + (i >> 4)) * NPT + n0 + (i & 15)];
      }
    }
    __syncthreads();
#pragma unroll
    for (int cc = 0; cc < 12; ++cc) {
      float4 a = *(const float4*)&f_lds[cc * 16 + nq * 4];
      const float* wp = &w_lds[ob * FT_WSTR + cc * 6];
      float2 w01 = *(const float2*)&wp[0];
      float2 w23 = *(const float2*)&wp[2];
      float2 w45 = *(const float2*)&wp[4];
      float w[6] = {w01.x, w01.y, w23.x, w23.y, w45.x, w45.y};
#pragma unroll
      for (int oo = 0; oo < 6; ++oo) {
        acc[0][oo] = fmaf(w[oo], a.x, acc[0][oo]);
        acc[1][oo] = fmaf(w[oo], a.y, acc[1][oo]);
        acc[2][oo] = fmaf(w[oo], a.z, acc[2][oo]);
        acc[3][oo] = fmaf(w[oo], a.w, acc[3][oo]);
      }
    }
  }

  float sq[4];
#pragma unroll
  for (int q = 0; q < 4; ++q) {
    float s = 0.f;
#pragma unroll
    for (int oo = 0; oo < 6; ++oo) s += acc[q][oo] * acc[q][oo];
    sq[q] = s;
  }
#pragma unroll
  for (int m = 1; m < 16; m <<= 1) {
#pragma unroll
    for (int q = 0; q < 4; ++q) sq[q] += __shfl_xor(sq[q], m);
  }

  float vnn[4][6];
  float sqn[4];
#pragma unroll
  for (int q = 0; q < 4; ++q) {
    float den = fmaxf(sqrtf(sq[q]), 1e-12f);
    float s = 0.f;
#pragma unroll
    for (int oo = 0; oo < 6; ++oo) {
      float v = acc[q][oo] / den;
      vnn[q][oo] = v;
      s += v * v;
    }
    sqn[q] = s;
  }
#pragma unroll
  for (int m = 1; m < 16; m <<= 1) {
#pragma unroll
    for (int q = 0; q < 4; ++q) sqn[q] += __shfl_xor(sqn[q], m);
  }

#pragma unroll
  for (int q = 0; q < 4; ++q) {
    int n = n0 + nq * 4 + q;
    unsigned short* fhr = fth + ((size_t)b * NPT + n) * NC + ob * 6;
    unsigned short* flr = ftl + ((size_t)b * NPT + n) * NC + ob * 6;
#pragma unroll
    for (int p2 = 0; p2 < 3; ++p2) {
      float v0 = acc[q][p2 * 2], v1 = acc[q][p2 * 2 + 1];
      unsigned short h0 = f32_to_bf16_rne(v0);
      unsigned short h1 = f32_to_bf16_rne(v1);
      float hv0 = __uint_as_float(((unsigned)h0) << 16);
      float hv1 = __uint_as_float(((unsigned)h1) << 16);
      unsigned short l0 = f32_to_bf16_rne(v0 - hv0);
      unsigned short l1 = f32_to_bf16_rne(v1 - hv1);
      *(unsigned*)&fhr[p2 * 2] = (unsigned)h0 | ((unsigned)h1 << 16);
      *(unsigned*)&flr[p2 * 2] = (unsigned)l0 | ((unsigned)l1 << 16);
    }
    float* fr = fnT + ((size_t)b * NPT + n) * RST;
#pragma unroll
    for (int oo = 0; oo < 6; ++oo) fr[ob * 6 + oo] = vnn[q][oo];
    if (ob == 0) fr[96] = sqn[q];
    unsigned short* hr = hiT + ((size_t)b * NPT + n) * NC + ob * 6;
    unsigned short* lr = loT + ((size_t)b * NPT + n) * NC + ob * 6;
#pragma unroll
    for (int p2 = 0; p2 < 3; ++p2) {
      float v0 = vnn[q][p2 * 2], v1 = vnn[q][p2 * 2 + 1];
      unsigned short h0 = f32_to_bf16_rne(v0);
      unsigned short h1 = f32_to_bf16_rne(v1);
      float hv0 = __uint_as_float(((unsigned)h0) << 16);
      float hv1 = __uint_as_float(((unsigned)h1) << 16);
      unsigned short l0 = f32_to_bf16_rne(v0 - hv0);
      unsigned short l1 = f32_to_bf16_rne(v1 - hv1);
      *(unsigned*)&hr[p2 * 2] = (unsigned)h0 | ((unsigned)h1 << 16);
      *(unsigned*)&lr[p2 * 2] = (unsigned)l0 | ((unsigned)l1 << 16);
    }
  }
}

// ---------------- K3: KNN candidate gen via compensated bf16 MFMA ----------------------
// 1-deep software pipeline: tile t+1's A-fragments are loaded before tile t's
// MFMA+selection, hiding the ~200cy L2 latency under ~780cy of compute.
__global__ __launch_bounds__(256, 4) void k_knn(const unsigned short* __restrict__ hiT,
                                                const unsigned short* __restrict__ loT,
                                                unsigned* __restrict__ pk) {
  int bid = blockIdx.x;
  int b = bid & 7;            // XCD affinity
  int r2 = bid >> 3;          // 0..391
  int iblk = r2 % 98;
  int jp = r2 / 98;           // 0..3
  int wq = threadIdx.x >> 6;
  int jsplit = jp * 4 + wq;   // 0..15
  int lane = threadIdx.x & 63;
  int col = lane & 31;
  int half = lane >> 5;
  int i = iblk * 32 + col;

  const unsigned short* hb = hiT + (size_t)b * NPT * NC;
  const unsigned short* lb = loT + (size_t)b * NPT * NC;

  short8 Bh[6], Bl[6];
  {
    const unsigned short* ih = hb + (size_t)i * NC + half * 8;
    const unsigned short* il = lb + (size_t)i * NC + half * 8;
#pragma unroll
    for (int ch = 0; ch < 6; ++ch) {
      Bh[ch] = *(const short8*)(ih + ch * 16);
      Bl[ch] = *(const short8*)(il + ch * 16);
    }
  }

  float kk[NDEP];
#pragma unroll
  for (int k = 0; k < NDEP; ++k) kk[k] = 0.0f;   // 0.0 < any real key (+1..3)

  int t0 = (98 * jsplit) >> 4, t1 = (98 * (jsplit + 1)) >> 4;
  int jbase = t0 * 32;

  short8 An[6];
  {
    const unsigned short* ah0 = hb + (size_t)(t0 * 32 + col) * NC + half * 8;
#pragma unroll
    for (int ch = 0; ch < 6; ++ch) An[ch] = *(const short8*)(ah0 + ch * 16);
  }

  for (int t = t0; t < t1; ++t) {
    int j0 = t * 32;
    short8 A[6];
#pragma unroll
    for (int ch = 0; ch < 6; ++ch) A[ch] = An[ch];
    if (t + 1 < t1) {  // prefetch next tile's A-fragments (overlaps MFMA+selection)
      const unsigned short* ah2 = hb + (size_t)((t + 1) * 32 + col) * NC + half * 8;
#pragma unroll
      for (int ch = 0; ch < 6; ++ch) An[ch] = *(const short8*)(ah2 + ch * 16);
    }
    f32x16 acc0, acc1;
#pragma unroll
    for (int r = 0; r < 16; ++r) { acc0[r] = 2.0f; acc1[r] = 0.f; }
#pragma unroll
    for (int ch = 0; ch < 6; ++ch)
      acc0 = __builtin_amdgcn_mfma_f32_32x32x16_bf16(A[ch], Bh[ch], acc0, 0, 0, 0);
#pragma unroll
    for (int ch = 0; ch < 6; ++ch)
      acc1 = __builtin_amdgcn_mfma_f32_32x32x16_bf16(A[ch], Bl[ch], acc1, 0, 0, 0);
    unsigned relbase = (unsigned)(j0 - jbase + 4 * half);
#pragma unroll
    for (int r = 0; r < 16; ++r) {
      float s = acc0[r] + acc1[r];            // = score + 2.0 (positive, in [1,3])
      unsigned kb = __float_as_uint(s);
      unsigned keyu = (kb & 0xFFFFFE00u) | (relbase + (unsigned)((r & 3) + 8 * (r >> 2)));
      float e = __uint_as_float(keyu);
#pragma unroll
      for (int s8 = NDEP - 1; s8 > 0; --s8)
        kk[s8] = __builtin_amdgcn_fmed3f(kk[s8 - 1], kk[s8], e);
      kk[0] = fmaxf(kk[0], e);
    }
  }

  // in-wave half-merge: top-9 of the two disjoint half-lists (merge-path identity)
  float c[NDEP];
#pragma unroll
  for (int k = 0; k < NDEP; ++k) {
    float pv = __shfl_xor(kk[NDEP - 1 - k], 32);
    c[k] = fmaxf(kk[k], pv);
  }
  if (half == 0) {
    unsigned* op = pk + (size_t)((size_t)b * NPT + i) * (NLIST * NDEP) + jsplit * NDEP;
#pragma unroll
    for (int k = 0; k < NDEP; ++k) op[k] = __float_as_uint(c[k]);
  }
}

// ------- K3b: fused select: u32 tournament top-16 -> f32 rescore -> exact top-9 --------
__global__ __launch_bounds__(256) void k_select(const unsigned* __restrict__ pk,
                                                const float* __restrict__ fnT,
                                                int* __restrict__ nn_idx) {
  int wid = threadIdx.x >> 6, lane = threadIdx.x & 63;
  int bid = blockIdx.x;                    // grid exact: NROWS/4
  int b = bid & 7;                         // XCD affinity
  int rg = bid >> 3;                       // 0..783
  int row = b * NPT + rg * 4 + wid;
  // prefetch own-row fragment (used in phase B, ~1000cy later)
  int sub = lane & 3;
  const float* fi = fnT + (size_t)row * RST + sub * 24;
  float4 fiv[6];
#pragma unroll
  for (int c4 = 0; c4 < 6; ++c4) fiv[c4] = *(const float4*)&fi[c4 * 4];

  const unsigned* p = pk + (size_t)row * (NLIST * NDEP);
  unsigned e0 = 0, e1 = 0, e2 = 0, e3 = 0;
  if (lane < 36) {
    uint4 v = *(const uint4*)&p[lane * 4];
    int g0 = lane * 4;
    int s0 = g0 / 9, s1 = (g0 + 1) / 9, s2 = (g0 + 2) / 9, s3 = (g0 + 3) / 9;
    int jb0 = ((98 * s0) >> 4) << 5, jb1 = ((98 * s1) >> 4) << 5;
    int jb2 = ((98 * s2) >> 4) << 5, jb3 = ((98 * s3) >> 4) << 5;
    // key = score bits[31:12] | global j (12 bits); unique since j unique
    e0 = (v.x & 0xFFFFF000u) | (unsigned)(jb0 + (int)(v.x & 0x1FFu));
    e1 = (v.y & 0xFFFFF000u) | (unsigned)(jb1 + (int)(v.y & 0x1FFu));
    e2 = (v.z & 0xFFFFF000u) | (unsigned)(jb2 + (int)(v.z & 0x1FFu));
    e3 = (v.w & 0xFFFFF000u) | (unsigned)(jb3 + (int)(v.w & 0x1FFu));
  }
  int myj = 0;
  for (int r = 0; r < NCAND; ++r) {
    unsigned a = e0 > e1 ? e0 : e1;
    unsigned bmx = e2 > e3 ? e2 : e3;
    unsigned loc = a > bmx ? a : bmx;
#pragma unroll
    for (int m = 1; m < 64; m <<= 1) {
      unsigned o = __shfl_xor(loc, m);
      loc = o > loc ? o : loc;
    }
    e0 = (e0 == loc) ? 0 : e0;
    e1 = (e1 == loc) ? 0 : e1;
    e2 = (e2 == loc) ? 0 : e2;
    e3 = (e3 == loc) ? 0 : e3;
    if ((lane >> 2) == r) myj = (int)(loc & 0xFFFu);
  }
  // Phase B: rescore candidate myj (4 lanes per candidate group)
  const float* fj = fnT + (size_t)((size_t)b * NPT + myj) * RST + sub * 24;
  float pd = 0.f;
#pragma unroll
  for (int c4 = 0; c4 < 6; ++c4) {
    float4 a4 = fiv[c4];
    float4 v4 = *(const float4*)&fj[c4 * 4];
    pd = fmaf(a4.x, v4.x, pd); pd = fmaf(a4.y, v4.y, pd);
    pd = fmaf(a4.z, v4.z, pd); pd = fmaf(a4.w, v4.w, pd);
  }
  pd += __shfl_xor(pd, 1);
  pd += __shfl_xor(pd, 2);
  u64 mykey = ~0ull;
  if (sub == 0) {
    float sqj = fnT[(size_t)((size_t)b * NPT + myj) * RST + 96];
    float score = fmaf(-0.5f, sqj, pd);
    mykey = ((u64)score_to_key_exact(score) << 32) | (unsigned)myj;
  }
  // Phase C: rank-based top-9 ordering (independent broadcasts, no serial chain)
  u64 kt[NCAND];
#pragma unroll
  for (int t = 0; t < NCAND; ++t) kt[t] = shfl64(mykey, t * 4);
  if (sub == 0) {
    int rank = 0;
#pragma unroll
    for (int t = 0; t < NCAND; ++t) rank += (kt[t] < mykey) ? 1 : 0;
    if (rank < NK) {
      int* op = nn_idx + (size_t)row * NK;
      op[rank] = (int)(mykey & 0xFFFu);
    }
  }
}

// ---------------- K4: u (f32, +bg) and v (bf16) halves via compensated bf16 MFMA -------
__global__ __launch_bounds__(256, 4) void k_uv(const unsigned short* __restrict__ fth,
                                               const unsigned short* __restrict__ ftl,
                                               const unsigned short* __restrict__ Wuvh,
                                               const unsigned short* __restrict__ Wuvl,
                                               const float* __restrict__ bg,
                                               float* __restrict__ uvu,
                                               unsigned short* __restrict__ uvv) {
  int bid = blockIdx.x;        // 2352 = 8b * 98nt * 3og
  int b = bid & 7;
  int t = bid >> 3;            // 0..293
  int nt = t % 98;
  int og = t / 98;             // 0..2
  int w = threadIdx.x >> 6;
  int ot = og * 4 + w;         // 0..11
  int lane = threadIdx.x & 63;
  int col = lane & 31, half = lane >> 5;
  int n0 = nt * 32, o0 = ot * 32;

  const unsigned short* fhp = fth + ((size_t)b * NPT + n0 + col) * NC + half * 8;
  const unsigned short* flp = ftl + ((size_t)b * NPT + n0 + col) * NC + half * 8;
  const unsigned short* whp = Wuvh + (size_t)(o0 + col) * NC + half * 8;
  const unsigned short* wlp = Wuvl + (size_t)(o0 + col) * NC + half * 8;

  f32x16 acc0, acc1;
#pragma unroll
  for (int r = 0; r < 16; ++r) { acc0[r] = 0.f; acc1[r] = 0.f; }
#pragma unroll
  for (int ch = 0; ch < 6; ++ch) {
    short8 ahv = *(const short8*)(fhp + ch * 16);
    short8 alv = *(const short8*)(flp + ch * 16);
    short8 bhv = *(const short8*)(whp + ch * 16);
    short8 blv = *(const short8*)(wlp + ch * 16);
    acc0 = __builtin_amdgcn_mfma_f32_32x32x16_bf16(ahv, bhv, acc0, 0, 0, 0);
    acc1 = __builtin_amdgcn_mfma_f32_32x32x16_bf16(ahv, blv, acc1, 0, 0, 0);
    acc0 = __builtin_amdgcn_mfma_f32_32x32x16_bf16(alv, bhv, acc0, 0, 0, 0);
  }

  int o = o0 + col;
  if (o0 < NC2) {  // u half: f32 + bias
    float bias = bg[o];
    float* up = uvu + ((size_t)b * NPT + n0) * NC2 + o;
#pragma unroll
    for (int r = 0; r < 16; ++r) {
      int nrow = (r & 3) + 8 * (r >> 2) + 4 * half;
      up[(size_t)nrow * NC2] = acc0[r] + acc1[r] + bias;
    }
  } else {         // v half: bf16
    unsigned short* vp = uvv + ((size_t)b * NPT + n0) * NC2 + (o - NC2);
#pragma unroll
    for (int r = 0; r < 16; ++r) {
      int nrow = (r & 3) + 8 * (r >> 2) + 4 * half;
      vp[(size_t)nrow * NC2] = f32_to_bf16_rne(acc0[r] + acc1[r]);
    }
  }
}

// ---------------- K5: agg = relu(max_k (u + v[idx])) -> bf16 hi/lo rows [n][192] -------
__global__ __launch_bounds__(192) void k_gather(const float* __restrict__ uvu,
                                                const unsigned short* __restrict__ uvv,
                                                const int* __restrict__ nn_idx,
                                                unsigned short* __restrict__ aggh,
                                                unsigned short* __restrict__ aggl) {
  int bid = blockIdx.x;
  int b = bid & 7;      // XCD affinity: per-batch v table (1.2 MB bf16) is L2-resident
  int ng = bid >> 3;    // 0..783
  int tid = threadIdx.x;
  int nq = tid / 48, c4 = tid % 48;
  int n = ng * 4 + nq;
  const float* ub = uvu + (size_t)b * NPT * NC2;
  const unsigned short* vb = uvv + (size_t)b * NPT * NC2;
  const int* ip = nn_idx + ((size_t)b * NPT + n) * NK;
  float4 u = *(const float4*)&ub[(size_t)n * NC2 + c4 * 4];
  float4 acc = make_float4(-1e30f, -1e30f, -1e30f, -1e30f);
#pragma unroll
  for (int k = 0; k < NK; ++k) {
    int j = ip[k];
    ushort4 vv = *(const ushort4*)&vb[(size_t)j * NC2 + c4 * 4];
    float vx = __uint_as_float(((unsigned)vv.x) << 16);
    float vy = __uint_as_float(((unsigned)vv.y) << 16);
    float vz = __uint_as_float(((unsigned)vv.z) << 16);
    float vw = __uint_as_float(((unsigned)vv.w) << 16);
    acc.x = fmaxf(acc.x, u.x + vx);
    acc.y = fmaxf(acc.y, u.y + vy);
    acc.z = fmaxf(acc.z, u.z + vz);
    acc.w = fmaxf(acc.w, u.w + vw);
  }
  float o4[4];
  o4[0] = fmaxf(acc.x, 0.f); o4[1] = fmaxf(acc.y, 0.f);
  o4[2] = fmaxf(acc.z, 0.f); o4[3] = fmaxf(acc.w, 0.f);
  u64 hp = 0, lp = 0;
#pragma unroll
  for (int e = 0; e < 4; ++e) {
    unsigned short h = f32_to_bf16_rne(o4[e]);
    float hv = __uint_as_float(((unsigned)h) << 16);
    unsigned short l = f32_to_bf16_rne(o4[e] - hv);
    hp |= ((u64)h) << (16 * e);
    lp |= ((u64)l) << (16 * e);
  }
  size_t off = ((size_t)b * NPT + n) * NC2 + c4 * 4;
  *(u64*)&aggh[off] = hp;
  *(u64*)&aggl[off] = lp;
}

// ---------------- K6: out = W2 @ agg + b2f + residual, via compensated bf16 MFMA -------
__global__ __launch_bounds__(64, 4) void k_out(const unsigned short* __restrict__ W2h,
                                               const unsigned short* __restrict__ W2l,
                                               const unsigned short* __restrict__ aggh,
                                               const unsigned short* __restrict__ aggl,
                                               const float* __restrict__ b2f,
                                               const float* __restrict__ x,
                                               float* __restrict__ out) {
  int bid = blockIdx.x;        // 2352 = 8b * 98nt * 3ot
  int b = bid & 7;
  int t = bid >> 3;            // 0..293
  int nt = t % 98;
  int ot = t / 98;             // 0..2
  int lane = threadIdx.x;
  int col = lane & 31, half = lane >> 5;
  int n0 = nt * 32, o0 = ot * 32;

  const unsigned short* whp = W2h + (size_t)(o0 + col) * NC2 + half * 8;
  const unsigned short* wlp = W2l + (size_t)(o0 + col) * NC2 + half * 8;
  const unsigned short* ahp = aggh + ((size_t)b * NPT + n0 + col) * NC2 + half * 8;
  const unsigned short* alp = aggl + ((size_t)b * NPT + n0 + col) * NC2 + half * 8;

  f32x16 acc0, acc1;
#pragma unroll
  for (int r = 0; r < 16; ++r) { acc0[r] = 0.f; acc1[r] = 0.f; }
#pragma unroll
  for (int ch = 0; ch < 12; ++ch) {
    short8 whv = *(const short8*)(whp + ch * 16);
    short8 wlv = *(const short8*)(wlp + ch * 16);
    short8 ahv = *(const short8*)(ahp + ch * 16);
    short8 alv = *(const short8*)(alp + ch * 16);
    acc0 = __builtin_amdgcn_mfma_f32_32x32x16_bf16(whv, ahv, acc0, 0, 0, 0);
    acc1 = __builtin_amdgcn_mfma_f32_32x32x16_bf16(whv, alv, acc1, 0, 0, 0);
    acc0 = __builtin_amdgcn_mfma_f32_32x32x16_bf16(wlv, ahv, acc0, 0, 0, 0);
  }

  int n = n0 + col;
  const float* xb = x + (size_t)b * NC * NPT;
  float* ob = out + (size_t)b * NC * NPT;
#pragma unroll
  for (int r = 0; r < 16; ++r) {
    int orow = o0 + (r & 3) + 8 * (r >> 2) + 4 * half;
    float v = acc0[r] + acc1[r] + b2f[orow] + xb[(size_t)orow * NPT + n];
    ob[(size_t)orow * NPT + n] = v;
  }
}

extern "C" void kernel_launch(void* const* d_in, const int* in_sizes, int n_in,
                              void* d_out, int out_size, void* d_ws, size_t ws_size,
                              hipStream_t stream) {
  const float* x  = (const float*)d_in[0];
  const float* W1 = (const float*)d_in[1];
  const float* b1 = (const float*)d_in[2];
  const float* g1 = (const float*)d_in[3];
  const float* be1= (const float*)d_in[4];
  const float* m1 = (const float*)d_in[5];
  const float* v1 = (const float*)d_in[6];
  const float* Wg = (const float*)d_in[7];
  const float* bg = (const float*)d_in[8];
  const float* W2 = (const float*)d_in[9];
  const float* b2 = (const float*)d_in[10];
  const float* g2 = (const float*)d_in[11];
  const float* be2= (const float*)d_in[12];
  const float* m2 = (const float*)d_in[13];
  const float* v2 = (const float*)d_in[14];
  float* out = (float*)d_out;

  float* ws = (float*)d_ws;
  size_t off = 0;
  unsigned short* fth = (unsigned short*)(ws + off); off += (size_t)NB * NPT * NC / 2;  // 4.8 MB
  unsigned short* ftl = (unsigned short*)(ws + off); off += (size_t)NB * NPT * NC / 2;  // 4.8 MB
  unsigned short* hiT = (unsigned short*)(ws + off); off += (size_t)NB * NPT * NC / 2;  // 4.8 MB
  unsigned short* loT = (unsigned short*)(ws + off); off += (size_t)NB * NPT * NC / 2;  // 4.8 MB
  float* uvu  = ws + off; off += (size_t)NB * NPT * NC2;            // 19.3 MB (u half, f32)
  unsigned short* uvv = (unsigned short*)(ws + off); off += (size_t)NB * NPT * NC2 / 2; // 9.6 MB
  float* aggr = ws + off; off += (size_t)NB * NPT * NC2;            // 19.3 MB (fnT / aggh+aggl)
  float* W1s  = ws + off; off += NC * NC;
  unsigned short* Wuvh = (unsigned short*)(ws + off); off += NC * NC2;      // 36864 u16
  unsigned short* Wuvl = (unsigned short*)(ws + off); off += NC * NC2;
  unsigned short* W2h  = (unsigned short*)(ws + off); off += NC * NC2 / 2;  // 18432 u16
  unsigned short* W2l  = (unsigned short*)(ws + off); off += NC * NC2 / 2;
  float* b1f  = ws + off; off += 128;
  float* b2f  = ws + off; off += 128;

  // Phase-disjoint overlays:
  //   fnT (10.4 MB) in aggr region; dead after k_select.
  //   aggh/aggl (9.6+9.6 MB) in aggr region; written by k_gather (after select).
  //   pk (14.5 MB) overlays uvu (19.3 MB); consumed by k_select before k_uv writes.
  //   nn_idx -> loT region (dead after k_knn).
  float* fnT    = aggr;
  unsigned short* aggh = (unsigned short*)aggr;
  unsigned short* aggl = aggh + (size_t)NB * NPT * NC2;
  unsigned* pk  = (unsigned*)uvu;
  int* nn_idx   = (int*)loT;

  k_fuse<<<dim3(64), 256, 0, stream>>>(W1, b1, g1, be1, m1, v1, Wg, W2, b2, g2, be2, m2, v2,
                                       W1s, b1f, Wuvh, Wuvl, W2h, W2l, b2f);
  k_feat<<<dim3(NB * 196), 64, 0, stream>>>(x, W1s, b1f, fth, ftl, fnT, hiT, loT);
  k_knn<<<dim3(NB * 98 * 4), 256, 0, stream>>>(hiT, loT, pk);
  k_select<<<dim3(NROWS / 4), 256, 0, stream>>>(pk, fnT, nn_idx);
  k_uv<<<dim3(NB * 98 * 3), 256, 0, stream>>>(fth, ftl, Wuvh, Wuvl, bg, uvu, uvv);
  k_gather<<<dim3(NB * NPT / 4), 192, 0, stream>>>(uvu, uvv, nn_idx, aggh, aggl);
  k_out<<<dim3(NB * 98 * 3), 64, 0, stream>>>(W2h, W2l, aggh, aggl, b2f, x, out);
}

// Round 19
// 172.882 us; speedup vs baseline: 1.1713x; 1.1713x over previous
//
#include <hip/hip_runtime.h>
#include <cstdint>

#define NB 8
#define NC 96
#define NC2 192
#define NPT 3136    // 56*56
#define NK 9
#define NSPL 16     // j-splits
#define NLIST 16    // lists per row after in-wave half-merge
#define NDEP 9      // per-list depth (>= NK for superset guarantee)
#define NCAND 16    // pooled candidate count per row
#define NROWS (NB * NPT)
#define RST 104     // fnT row stride (96 fn + sq at [96] + pad)
#define FT_WSTR 76  // k_feat LDS per-ob stride
static constexpr float BN_EPS = 1e-5f;
typedef unsigned long long u64;
typedef float f32x16 __attribute__((ext_vector_type(16)));
typedef short short8 __attribute__((ext_vector_type(8)));

__device__ inline unsigned short f32_to_bf16_rne(float x) {
  unsigned u = __float_as_uint(x);
  unsigned r = (u + 0x7FFFu + ((u >> 16) & 1u)) >> 16;
  return (unsigned short)r;
}

__device__ inline unsigned score_to_key_exact(float s) {
  unsigned u = __float_as_uint(s);
  u ^= 0x80000000u | (unsigned)((int)u >> 31);  // monotone increasing map
  return ~u;                                    // descending score = ascending dist
}

__device__ inline u64 shfl64(u64 x, int src) {
  unsigned lo = __shfl((unsigned)x, src);
  unsigned hi = __shfl((unsigned)(x >> 32), src);
  return ((u64)hi << 32) | lo;
}

// ---------------- K1: fold BN into weights; bf16 hi/lo weight layouts ------------------
__global__ void k_fuse(const float* __restrict__ W1, const float* __restrict__ b1,
                       const float* __restrict__ g1, const float* __restrict__ be1,
                       const float* __restrict__ m1, const float* __restrict__ v1,
                       const float* __restrict__ Wg,
                       const float* __restrict__ W2, const float* __restrict__ b2,
                       const float* __restrict__ g2, const float* __restrict__ be2,
                       const float* __restrict__ m2, const float* __restrict__ v2,
                       float* __restrict__ W1s, float* __restrict__ b1f,
                       unsigned short* __restrict__ Wuvh, unsigned short* __restrict__ Wuvl,
                       unsigned short* __restrict__ W2h, unsigned short* __restrict__ W2l,
                       float* __restrict__ b2f) {
  int t = blockIdx.x * blockDim.x + threadIdx.x;
  int nth = gridDim.x * blockDim.x;
  for (int i = t; i < NC * NC; i += nth) {
    int ch = i / 1152, r = i % 1152;
    int ob = r / 72, r2 = r % 72;
    int cc = r2 / 6, oo = r2 % 6;
    int c = ch * 12 + cc, o = ob * 6 + oo;
    float inv = g1[o] / sqrtf(v1[o] + BN_EPS);
    W1s[i] = W1[o * NC + c] * inv;
  }
  for (int o = t; o < NC; o += nth) {
    float inv = g1[o] / sqrtf(v1[o] + BN_EPS);
    b1f[o] = b1[o] * inv + be1[o] - m1[o] * inv;
    float inv2v = g2[o] / sqrtf(v2[o] + BN_EPS);
    b2f[o] = b2[o] * inv2v + be2[o] - m2[o] * inv2v;
  }
  for (int i = t; i < 2 * NC2 * NC; i += nth) {
    int o4 = i / NC, c = i % NC;
    float val;
    if (o4 < NC2) val = Wg[o4 * NC2 + c] - Wg[o4 * NC2 + NC + c];
    else          val = Wg[(o4 - NC2) * NC2 + NC + c];
    unsigned short h = f32_to_bf16_rne(val);
    float hv = __uint_as_float(((unsigned)h) << 16);
    Wuvh[i] = h;
    Wuvl[i] = f32_to_bf16_rne(val - hv);
  }
  for (int i = t; i < NC * NC2; i += nth) {
    int o = i / NC2, c = i % NC2;
    float inv = g2[o] / sqrtf(v2[o] + BN_EPS);
    float val = W2[o * NC2 + c] * inv;
    unsigned short h = f32_to_bf16_rne(val);
    float hv = __uint_as_float(((unsigned)h) << 16);
    W2h[i] = h;
    W2l[i] = f32_to_bf16_rne(val - hv);
  }
}

// ------- K2: feat = BN(W1 x + b1) -> bf16 hi/lo rows; fnT f32 norm rows; hiT/loT -------
__global__ __launch_bounds__(64, 4) void k_feat(const float* __restrict__ x,
                                                const float* __restrict__ W1s,
                                                const float* __restrict__ b1f,
                                                unsigned short* __restrict__ fth,
                                                unsigned short* __restrict__ ftl,
                                                float* __restrict__ fnT,
                                                unsigned short* __restrict__ hiT,
                                                unsigned short* __restrict__ loT) {
  int bid = blockIdx.x;      // 1568
  int b = bid & 7;
  int ng = bid >> 3;         // 0..195
  int n0 = ng * 16;
  int lane = threadIdx.x;
  int ob = lane & 15, nq = lane >> 4;

  __shared__ float w_lds[16 * FT_WSTR];  // 4864 B
  __shared__ float f_lds[12 * 16];       // 768 B

  const float* xb = x + (size_t)b * NC * NPT;
  float acc[4][6];
#pragma unroll
  for (int oo = 0; oo < 6; ++oo) {
    float bv = b1f[ob * 6 + oo];
#pragma unroll
    for (int q = 0; q < 4; ++q) acc[q][oo] = bv;
  }

  for (int ch = 0; ch < 8; ++ch) {
    __syncthreads();
    {
      const float* wsrc = W1s + ch * 1152;
#pragma unroll
      for (int it = 0; it < 5; ++it) {
        int i = it * 256 + lane * 4;
        if (it < 4 || lane < 32) {
          float4 v = *(const float4*)&wsrc[i];
          *(float4*)&w_lds[(i / 72) * FT_WSTR + (i % 72)] = v;
        }
      }
#pragma unroll
      for (int it = 0; it < 3; ++it) {
        int i = it * 64 + lane;
        f_lds[i] = xb[(size_t)(ch * 12 + (i >> 4)) * NPT + n0 + (i & 15)];
      }
    }
    __syncthreads();
#pragma unroll
    for (int cc = 0; cc < 12; ++cc) {
      float4 a = *(const float4*)&f_lds[cc * 16 + nq * 4];
      const float* wp = &w_lds[ob * FT_WSTR + cc * 6];
      float2 w01 = *(const float2*)&wp[0];
      float2 w23 = *(const float2*)&wp[2];
      float2 w45 = *(const float2*)&wp[4];
      float w[6] = {w01.x, w01.y, w23.x, w23.y, w45.x, w45.y};
#pragma unroll
      for (int oo = 0; oo < 6; ++oo) {
        acc[0][oo] = fmaf(w[oo], a.x, acc[0][oo]);
        acc[1][oo] = fmaf(w[oo], a.y, acc[1][oo]);
        acc[2][oo] = fmaf(w[oo], a.z, acc[2][oo]);
        acc[3][oo] = fmaf(w[oo], a.w, acc[3][oo]);
      }
    }
  }

  float sq[4];
#pragma unroll
  for (int q = 0; q < 4; ++q) {
    float s = 0.f;
#pragma unroll
    for (int oo = 0; oo < 6; ++oo) s += acc[q][oo] * acc[q][oo];
    sq[q] = s;
  }
#pragma unroll
  for (int m = 1; m < 16; m <<= 1) {
#pragma unroll
    for (int q = 0; q < 4; ++q) sq[q] += __shfl_xor(sq[q], m);
  }

  float vnn[4][6];
  float sqn[4];
#pragma unroll
  for (int q = 0; q < 4; ++q) {
    float den = fmaxf(sqrtf(sq[q]), 1e-12f);
    float s = 0.f;
#pragma unroll
    for (int oo = 0; oo < 6; ++oo) {
      float v = acc[q][oo] / den;
      vnn[q][oo] = v;
      s += v * v;
    }
    sqn[q] = s;
  }
#pragma unroll
  for (int m = 1; m < 16; m <<= 1) {
#pragma unroll
    for (int q = 0; q < 4; ++q) sqn[q] += __shfl_xor(sqn[q], m);
  }

#pragma unroll
  for (int q = 0; q < 4; ++q) {
    int n = n0 + nq * 4 + q;
    unsigned short* fhr = fth + ((size_t)b * NPT + n) * NC + ob * 6;
    unsigned short* flr = ftl + ((size_t)b * NPT + n) * NC + ob * 6;
#pragma unroll
    for (int p2 = 0; p2 < 3; ++p2) {
      float v0 = acc[q][p2 * 2], v1 = acc[q][p2 * 2 + 1];
      unsigned short h0 = f32_to_bf16_rne(v0);
      unsigned short h1 = f32_to_bf16_rne(v1);
      float hv0 = __uint_as_float(((unsigned)h0) << 16);
      float hv1 = __uint_as_float(((unsigned)h1) << 16);
      unsigned short l0 = f32_to_bf16_rne(v0 - hv0);
      unsigned short l1 = f32_to_bf16_rne(v1 - hv1);
      *(unsigned*)&fhr[p2 * 2] = (unsigned)h0 | ((unsigned)h1 << 16);
      *(unsigned*)&flr[p2 * 2] = (unsigned)l0 | ((unsigned)l1 << 16);
    }
    float* fr = fnT + ((size_t)b * NPT + n) * RST;
#pragma unroll
    for (int oo = 0; oo < 6; ++oo) fr[ob * 6 + oo] = vnn[q][oo];
    if (ob == 0) fr[96] = sqn[q];
    unsigned short* hr = hiT + ((size_t)b * NPT + n) * NC + ob * 6;
    unsigned short* lr = loT + ((size_t)b * NPT + n) * NC + ob * 6;
#pragma unroll
    for (int p2 = 0; p2 < 3; ++p2) {
      float v0 = vnn[q][p2 * 2], v1 = vnn[q][p2 * 2 + 1];
      unsigned short h0 = f32_to_bf16_rne(v0);
      unsigned short h1 = f32_to_bf16_rne(v1);
      float hv0 = __uint_as_float(((unsigned)h0) << 16);
      float hv1 = __uint_as_float(((unsigned)h1) << 16);
      unsigned short l0 = f32_to_bf16_rne(v0 - hv0);
      unsigned short l1 = f32_to_bf16_rne(v1 - hv1);
      *(unsigned*)&hr[p2 * 2] = (unsigned)h0 | ((unsigned)h1 << 16);
      *(unsigned*)&lr[p2 * 2] = (unsigned)l0 | ((unsigned)l1 << 16);
    }
  }
}

// ---------------- K3: KNN candidate gen via compensated bf16 MFMA (R17 form) -----------
// Loads at point of use: cross-wave L2 reuse of A-tiles is the performance backbone
// (R18's register prefetch widened the in-flight footprint and quadrupled HBM FETCH).
__global__ __launch_bounds__(256, 4) void k_knn(const unsigned short* __restrict__ hiT,
                                                const unsigned short* __restrict__ loT,
                                                unsigned* __restrict__ pk) {
  int bid = blockIdx.x;
  int b = bid & 7;            // XCD affinity
  int r2 = bid >> 3;          // 0..391
  int iblk = r2 % 98;
  int jp = r2 / 98;           // 0..3
  int wq = threadIdx.x >> 6;
  int jsplit = jp * 4 + wq;   // 0..15
  int lane = threadIdx.x & 63;
  int col = lane & 31;
  int half = lane >> 5;
  int i = iblk * 32 + col;

  const unsigned short* hb = hiT + (size_t)b * NPT * NC;
  const unsigned short* lb = loT + (size_t)b * NPT * NC;

  short8 Bh[6], Bl[6];
  {
    const unsigned short* ih = hb + (size_t)i * NC + half * 8;
    const unsigned short* il = lb + (size_t)i * NC + half * 8;
#pragma unroll
    for (int ch = 0; ch < 6; ++ch) {
      Bh[ch] = *(const short8*)(ih + ch * 16);
      Bl[ch] = *(const short8*)(il + ch * 16);
    }
  }

  float kk[NDEP];
#pragma unroll
  for (int k = 0; k < NDEP; ++k) kk[k] = 0.0f;   // 0.0 < any real key (+1..3)

  int t0 = (98 * jsplit) >> 4, t1 = (98 * (jsplit + 1)) >> 4;
  int jbase = t0 * 32;
  for (int t = t0; t < t1; ++t) {
    int j0 = t * 32;
    const unsigned short* ah = hb + (size_t)(j0 + col) * NC + half * 8;
    f32x16 acc0, acc1;
#pragma unroll
    for (int r = 0; r < 16; ++r) { acc0[r] = 2.0f; acc1[r] = 0.f; }
    {
      short8 A[6];
#pragma unroll
      for (int ch = 0; ch < 6; ++ch) A[ch] = *(const short8*)(ah + ch * 16);
#pragma unroll
      for (int ch = 0; ch < 6; ++ch)
        acc0 = __builtin_amdgcn_mfma_f32_32x32x16_bf16(A[ch], Bh[ch], acc0, 0, 0, 0);
#pragma unroll
      for (int ch = 0; ch < 6; ++ch)
        acc1 = __builtin_amdgcn_mfma_f32_32x32x16_bf16(A[ch], Bl[ch], acc1, 0, 0, 0);
    }
    unsigned relbase = (unsigned)(j0 - jbase + 4 * half);
#pragma unroll
    for (int r = 0; r < 16; ++r) {
      float s = acc0[r] + acc1[r];            // = score + 2.0 (positive, in [1,3])
      unsigned kb = __float_as_uint(s);
      unsigned keyu = (kb & 0xFFFFFE00u) | (relbase + (unsigned)((r & 3) + 8 * (r >> 2)));
      float e = __uint_as_float(keyu);
#pragma unroll
      for (int s8 = NDEP - 1; s8 > 0; --s8)
        kk[s8] = __builtin_amdgcn_fmed3f(kk[s8 - 1], kk[s8], e);
      kk[0] = fmaxf(kk[0], e);
    }
  }

  // in-wave half-merge: top-9 of the two disjoint half-lists (merge-path identity)
  float c[NDEP];
#pragma unroll
  for (int k = 0; k < NDEP; ++k) {
    float pv = __shfl_xor(kk[NDEP - 1 - k], 32);
    c[k] = fmaxf(kk[k], pv);
  }
  if (half == 0) {
    unsigned* op = pk + (size_t)((size_t)b * NPT + i) * (NLIST * NDEP) + jsplit * NDEP;
#pragma unroll
    for (int k = 0; k < NDEP; ++k) op[k] = __float_as_uint(c[k]);
  }
}

// ------- K3b: fused select: u32 tournament top-16 -> f32 rescore -> exact top-9 --------
__global__ __launch_bounds__(256) void k_select(const unsigned* __restrict__ pk,
                                                const float* __restrict__ fnT,
                                                int* __restrict__ nn_idx) {
  int wid = threadIdx.x >> 6, lane = threadIdx.x & 63;
  int bid = blockIdx.x;                    // grid exact: NROWS/4
  int b = bid & 7;                         // XCD affinity
  int rg = bid >> 3;                       // 0..783
  int row = b * NPT + rg * 4 + wid;
  // prefetch own-row fragment (used in phase B, ~1000cy later; contiguous, no footprint cost)
  int sub = lane & 3;
  const float* fi = fnT + (size_t)row * RST + sub * 24;
  float4 fiv[6];
#pragma unroll
  for (int c4 = 0; c4 < 6; ++c4) fiv[c4] = *(const float4*)&fi[c4 * 4];

  const unsigned* p = pk + (size_t)row * (NLIST * NDEP);
  unsigned e0 = 0, e1 = 0, e2 = 0, e3 = 0;
  if (lane < 36) {
    uint4 v = *(const uint4*)&p[lane * 4];
    int g0 = lane * 4;
    int s0 = g0 / 9, s1 = (g0 + 1) / 9, s2 = (g0 + 2) / 9, s3 = (g0 + 3) / 9;
    int jb0 = ((98 * s0) >> 4) << 5, jb1 = ((98 * s1) >> 4) << 5;
    int jb2 = ((98 * s2) >> 4) << 5, jb3 = ((98 * s3) >> 4) << 5;
    // key = score bits[31:12] | global j (12 bits); unique since j unique
    e0 = (v.x & 0xFFFFF000u) | (unsigned)(jb0 + (int)(v.x & 0x1FFu));
    e1 = (v.y & 0xFFFFF000u) | (unsigned)(jb1 + (int)(v.y & 0x1FFu));
    e2 = (v.z & 0xFFFFF000u) | (unsigned)(jb2 + (int)(v.z & 0x1FFu));
    e3 = (v.w & 0xFFFFF000u) | (unsigned)(jb3 + (int)(v.w & 0x1FFu));
  }
  int myj = 0;
  for (int r = 0; r < NCAND; ++r) {
    unsigned a = e0 > e1 ? e0 : e1;
    unsigned bmx = e2 > e3 ? e2 : e3;
    unsigned loc = a > bmx ? a : bmx;
#pragma unroll
    for (int m = 1; m < 64; m <<= 1) {
      unsigned o = __shfl_xor(loc, m);
      loc = o > loc ? o : loc;
    }
    e0 = (e0 == loc) ? 0 : e0;
    e1 = (e1 == loc) ? 0 : e1;
    e2 = (e2 == loc) ? 0 : e2;
    e3 = (e3 == loc) ? 0 : e3;
    if ((lane >> 2) == r) myj = (int)(loc & 0xFFFu);
  }
  // Phase B: rescore candidate myj (4 lanes per candidate group)
  const float* fj = fnT + (size_t)((size_t)b * NPT + myj) * RST + sub * 24;
  float pd = 0.f;
#pragma unroll
  for (int c4 = 0; c4 < 6; ++c4) {
    float4 a4 = fiv[c4];
    float4 v4 = *(const float4*)&fj[c4 * 4];
    pd = fmaf(a4.x, v4.x, pd); pd = fmaf(a4.y, v4.y, pd);
    pd = fmaf(a4.z, v4.z, pd); pd = fmaf(a4.w, v4.w, pd);
  }
  pd += __shfl_xor(pd, 1);
  pd += __shfl_xor(pd, 2);
  u64 mykey = ~0ull;
  if (sub == 0) {
    float sqj = fnT[(size_t)((size_t)b * NPT + myj) * RST + 96];
    float score = fmaf(-0.5f, sqj, pd);
    mykey = ((u64)score_to_key_exact(score) << 32) | (unsigned)myj;
  }
  // Phase C: rank-based top-9 ordering (independent broadcasts, no serial chain)
  u64 kt[NCAND];
#pragma unroll
  for (int t = 0; t < NCAND; ++t) kt[t] = shfl64(mykey, t * 4);
  if (sub == 0) {
    int rank = 0;
#pragma unroll
    for (int t = 0; t < NCAND; ++t) rank += (kt[t] < mykey) ? 1 : 0;
    if (rank < NK) {
      int* op = nn_idx + (size_t)row * NK;
      op[rank] = (int)(mykey & 0xFFFu);
    }
  }
}

// ---------------- K4: u (f32, +bg) and v (bf16) halves via compensated bf16 MFMA -------
__global__ __launch_bounds__(256, 4) void k_uv(const unsigned short* __restrict__ fth,
                                               const unsigned short* __restrict__ ftl,
                                               const unsigned short* __restrict__ Wuvh,
                                               const unsigned short* __restrict__ Wuvl,
                                               const float* __restrict__ bg,
                                               float* __restrict__ uvu,
                                               unsigned short* __restrict__ uvv) {
  int bid = blockIdx.x;        // 2352 = 8b * 98nt * 3og
  int b = bid & 7;
  int t = bid >> 3;            // 0..293
  int nt = t % 98;
  int og = t / 98;             // 0..2
  int w = threadIdx.x >> 6;
  int ot = og * 4 + w;         // 0..11
  int lane = threadIdx.x & 63;
  int col = lane & 31, half = lane >> 5;
  int n0 = nt * 32, o0 = ot * 32;

  const unsigned short* fhp = fth + ((size_t)b * NPT + n0 + col) * NC + half * 8;
  const unsigned short* flp = ftl + ((size_t)b * NPT + n0 + col) * NC + half * 8;
  const unsigned short* whp = Wuvh + (size_t)(o0 + col) * NC + half * 8;
  const unsigned short* wlp = Wuvl + (size_t)(o0 + col) * NC + half * 8;

  f32x16 acc0, acc1;
#pragma unroll
  for (int r = 0; r < 16; ++r) { acc0[r] = 0.f; acc1[r] = 0.f; }
#pragma unroll
  for (int ch = 0; ch < 6; ++ch) {
    short8 ahv = *(const short8*)(fhp + ch * 16);
    short8 alv = *(const short8*)(flp + ch * 16);
    short8 bhv = *(const short8*)(whp + ch * 16);
    short8 blv = *(const short8*)(wlp + ch * 16);
    acc0 = __builtin_amdgcn_mfma_f32_32x32x16_bf16(ahv, bhv, acc0, 0, 0, 0);
    acc1 = __builtin_amdgcn_mfma_f32_32x32x16_bf16(ahv, blv, acc1, 0, 0, 0);
    acc0 = __builtin_amdgcn_mfma_f32_32x32x16_bf16(alv, bhv, acc0, 0, 0, 0);
  }

  int o = o0 + col;
  if (o0 < NC2) {  // u half: f32 + bias
    float bias = bg[o];
    float* up = uvu + ((size_t)b * NPT + n0) * NC2 + o;
#pragma unroll
    for (int r = 0; r < 16; ++r) {
      int nrow = (r & 3) + 8 * (r >> 2) + 4 * half;
      up[(size_t)nrow * NC2] = acc0[r] + acc1[r] + bias;
    }
  } else {         // v half: bf16
    unsigned short* vp = uvv + ((size_t)b * NPT + n0) * NC2 + (o - NC2);
#pragma unroll
    for (int r = 0; r < 16; ++r) {
      int nrow = (r & 3) + 8 * (r >> 2) + 4 * half;
      vp[(size_t)nrow * NC2] = f32_to_bf16_rne(acc0[r] + acc1[r]);
    }
  }
}

// ---------------- K5: agg = relu(max_k (u + v[idx])) -> bf16 hi/lo rows [n][192] -------
__global__ __launch_bounds__(192) void k_gather(const float* __restrict__ uvu,
                                                const unsigned short* __restrict__ uvv,
                                                const int* __restrict__ nn_idx,
                                                unsigned short* __restrict__ aggh,
                                                unsigned short* __restrict__ aggl) {
  int bid = blockIdx.x;
  int b = bid & 7;      // XCD affinity: per-batch v table (1.2 MB bf16) is L2-resident
  int ng = bid >> 3;    // 0..783
  int tid = threadIdx.x;
  int nq = tid / 48, c4 = tid % 48;
  int n = ng * 4 + nq;
  const float* ub = uvu + (size_t)b * NPT * NC2;
  const unsigned short* vb = uvv + (size_t)b * NPT * NC2;
  const int* ip = nn_idx + ((size_t)b * NPT + n) * NK;
  float4 u = *(const float4*)&ub[(size_t)n * NC2 + c4 * 4];
  float4 acc = make_float4(-1e30f, -1e30f, -1e30f, -1e30f);
#pragma unroll
  for (int k = 0; k < NK; ++k) {
    int j = ip[k];
    ushort4 vv = *(const ushort4*)&vb[(size_t)j * NC2 + c4 * 4];
    float vx = __uint_as_float(((unsigned)vv.x) << 16);
    float vy = __uint_as_float(((unsigned)vv.y) << 16);
    float vz = __uint_as_float(((unsigned)vv.z) << 16);
    float vw = __uint_as_float(((unsigned)vv.w) << 16);
    acc.x = fmaxf(acc.x, u.x + vx);
    acc.y = fmaxf(acc.y, u.y + vy);
    acc.z = fmaxf(acc.z, u.z + vz);
    acc.w = fmaxf(acc.w, u.w + vw);
  }
  float o4[4];
  o4[0] = fmaxf(acc.x, 0.f); o4[1] = fmaxf(acc.y, 0.f);
  o4[2] = fmaxf(acc.z, 0.f); o4[3] = fmaxf(acc.w, 0.f);
  u64 hp = 0, lp = 0;
#pragma unroll
  for (int e = 0; e < 4; ++e) {
    unsigned short h = f32_to_bf16_rne(o4[e]);
    float hv = __uint_as_float(((unsigned)h) << 16);
    unsigned short l = f32_to_bf16_rne(o4[e] - hv);
    hp |= ((u64)h) << (16 * e);
    lp |= ((u64)l) << (16 * e);
  }
  size_t off = ((size_t)b * NPT + n) * NC2 + c4 * 4;
  *(u64*)&aggh[off] = hp;
  *(u64*)&aggl[off] = lp;
}

// ---------------- K6: out = W2 @ agg + b2f + residual, via compensated bf16 MFMA -------
__global__ __launch_bounds__(64, 4) void k_out(const unsigned short* __restrict__ W2h,
                                               const unsigned short* __restrict__ W2l,
                                               const unsigned short* __restrict__ aggh,
                                               const unsigned short* __restrict__ aggl,
                                               const float* __restrict__ b2f,
                                               const float* __restrict__ x,
                                               float* __restrict__ out) {
  int bid = blockIdx.x;        // 2352 = 8b * 98nt * 3ot
  int b = bid & 7;
  int t = bid >> 3;            // 0..293
  int nt = t % 98;
  int ot = t / 98;             // 0..2
  int lane = threadIdx.x;
  int col = lane & 31, half = lane >> 5;
  int n0 = nt * 32, o0 = ot * 32;

  const unsigned short* whp = W2h + (size_t)(o0 + col) * NC2 + half * 8;
  const unsigned short* wlp = W2l + (size_t)(o0 + col) * NC2 + half * 8;
  const unsigned short* ahp = aggh + ((size_t)b * NPT + n0 + col) * NC2 + half * 8;
  const unsigned short* alp = aggl + ((size_t)b * NPT + n0 + col) * NC2 + half * 8;

  f32x16 acc0, acc1;
#pragma unroll
  for (int r = 0; r < 16; ++r) { acc0[r] = 0.f; acc1[r] = 0.f; }
#pragma unroll
  for (int ch = 0; ch < 12; ++ch) {
    short8 whv = *(const short8*)(whp + ch * 16);
    short8 wlv = *(const short8*)(wlp + ch * 16);
    short8 ahv = *(const short8*)(ahp + ch * 16);
    short8 alv = *(const short8*)(alp + ch * 16);
    acc0 = __builtin_amdgcn_mfma_f32_32x32x16_bf16(whv, ahv, acc0, 0, 0, 0);
    acc1 = __builtin_amdgcn_mfma_f32_32x32x16_bf16(whv, alv, acc1, 0, 0, 0);
    acc0 = __builtin_amdgcn_mfma_f32_32x32x16_bf16(wlv, ahv, acc0, 0, 0, 0);
  }

  int n = n0 + col;
  const float* xb = x + (size_t)b * NC * NPT;
  float* ob = out + (size_t)b * NC * NPT;
#pragma unroll
  for (int r = 0; r < 16; ++r) {
    int orow = o0 + (r & 3) + 8 * (r >> 2) + 4 * half;
    float v = acc0[r] + acc1[r] + b2f[orow] + xb[(size_t)orow * NPT + n];
    ob[(size_t)orow * NPT + n] = v;
  }
}

extern "C" void kernel_launch(void* const* d_in, const int* in_sizes, int n_in,
                              void* d_out, int out_size, void* d_ws, size_t ws_size,
                              hipStream_t stream) {
  const float* x  = (const float*)d_in[0];
  const float* W1 = (const float*)d_in[1];
  const float* b1 = (const float*)d_in[2];
  const float* g1 = (const float*)d_in[3];
  const float* be1= (const float*)d_in[4];
  const float* m1 = (const float*)d_in[5];
  const float* v1 = (const float*)d_in[6];
  const float* Wg = (const float*)d_in[7];
  const float* bg = (const float*)d_in[8];
  const float* W2 = (const float*)d_in[9];
  const float* b2 = (const float*)d_in[10];
  const float* g2 = (const float*)d_in[11];
  const float* be2= (const float*)d_in[12];
  const float* m2 = (const float*)d_in[13];
  const float* v2 = (const float*)d_in[14];
  float* out = (float*)d_out;

  float* ws = (float*)d_ws;
  size_t off = 0;
  unsigned short* fth = (unsigned short*)(ws + off); off += (size_t)NB * NPT * NC / 2;  // 4.8 MB
  unsigned short* ftl = (unsigned short*)(ws + off); off += (size_t)NB * NPT * NC / 2;  // 4.8 MB
  unsigned short* hiT = (unsigned short*)(ws + off); off += (size_t)NB * NPT * NC / 2;  // 4.8 MB
  unsigned short* loT = (unsigned short*)(ws + off); off += (size_t)NB * NPT * NC / 2;  // 4.8 MB
  float* uvu  = ws + off; off += (size_t)NB * NPT * NC2;            // 19.3 MB (u half, f32)
  unsigned short* uvv = (unsigned short*)(ws + off); off += (size_t)NB * NPT * NC2 / 2; // 9.6 MB
  float* aggr = ws + off; off += (size_t)NB * NPT * NC2;            // 19.3 MB (fnT / aggh+aggl)
  float* W1s  = ws + off; off += NC * NC;
  unsigned short* Wuvh = (unsigned short*)(ws + off); off += NC * NC2;      // 36864 u16
  unsigned short* Wuvl = (unsigned short*)(ws + off); off += NC * NC2;
  unsigned short* W2h  = (unsigned short*)(ws + off); off += NC * NC2 / 2;  // 18432 u16
  unsigned short* W2l  = (unsigned short*)(ws + off); off += NC * NC2 / 2;
  float* b1f  = ws + off; off += 128;
  float* b2f  = ws + off; off += 128;

  // Phase-disjoint overlays:
  //   fnT (10.4 MB) in aggr region; dead after k_select.
  //   aggh/aggl (9.6+9.6 MB) in aggr region; written by k_gather (after select).
  //   pk (14.5 MB) overlays uvu (19.3 MB); consumed by k_select before k_uv writes.
  //   nn_idx -> loT region (dead after k_knn).
  float* fnT    = aggr;
  unsigned short* aggh = (unsigned short*)aggr;
  unsigned short* aggl = aggh + (size_t)NB * NPT * NC2;
  unsigned* pk  = (unsigned*)uvu;
  int* nn_idx   = (int*)loT;

  k_fuse<<<dim3(64), 256, 0, stream>>>(W1, b1, g1, be1, m1, v1, Wg, W2, b2, g2, be2, m2, v2,
                                       W1s, b1f, Wuvh, Wuvl, W2h, W2l, b2f);
  k_feat<<<dim3(NB * 196), 64, 0, stream>>>(x, W1s, b1f, fth, ftl, fnT, hiT, loT);
  k_knn<<<dim3(NB * 98 * 4), 256, 0, stream>>>(hiT, loT, pk);
  k_select<<<dim3(NROWS / 4), 256, 0, stream>>>(pk, fnT, nn_idx);
  k_uv<<<dim3(NB * 98 * 3), 256, 0, stream>>>(fth, ftl, Wuvh, Wuvl, bg, uvu, uvv);
  k_gather<<<dim3(NB * NPT / 4), 192, 0, stream>>>(uvu, uvv, nn_idx, aggh, aggl);
  k_out<<<dim3(NB * 98 * 3), 64, 0, stream>>>(W2h, W2l, aggh, aggl, b2f, x, out);
}